// Round 23
// baseline (107.473 us; speedup 1.0000x reference)
//
#include <hip/hip_runtime.h>

#define NPIX 704
#define NIMG 24
#define NB 4
#define NCAM 6
#define DB 59
#define CT 64
#define P_TOT (NIMG*NPIX*DB)   // 996864
#define NVOX 65536             // 4 batches * 128*128 (gz==0 only)
#define SLC 32                 // histogram slices (contention spreading)
#define NKEY (NVOX*SLC)        // 2,097,152
#define CHUNK 64
#define SCAN_BLKS (NKEY/1024)  // 2048
#define MPIX (NIMG*NPIX)       // 16896
#define OUT_F4 (NB*64*16384/4) // 1,048,576 float4 (outT)
#define HIST_F4 (NKEY/4)       // 524,288 float4 in hist
#define GEMM_BLKS (MPIX/32)    // 528
#define GEOM_BLKS (MPIX/4)     // 4224

typedef unsigned short u16;
typedef unsigned long long u64;
typedef __attribute__((ext_vector_type(8))) unsigned short u16x8;
typedef __attribute__((ext_vector_type(4))) __bf16 bf16x4;
typedef __attribute__((ext_vector_type(8))) __bf16 bf16x8;
typedef __attribute__((ext_vector_type(4))) float f32x4;

__device__ inline u16 f2bf(float f) {          // RN float->bf16
  unsigned u = __float_as_uint(f);
  u += 0x7FFFu + ((u >> 16) & 1u);
  return (u16)(u >> 16);
}

// ---------------------------------------------------------------------------
// Kernel 1: fused prep — blocks 0..255 pack W (bf16, staging order),
// block 256 per-(b,n) matrix prep, blocks 257.. zero outT + hist.
// ---------------------------------------------------------------------------
__device__ inline void inv3(const double a[9], double o[9]) {
  double c0 = a[4]*a[8] - a[5]*a[7];
  double c1 = a[3]*a[8] - a[5]*a[6];
  double c2 = a[3]*a[7] - a[4]*a[6];
  double det = a[0]*c0 - a[1]*c1 + a[2]*c2;
  double id = 1.0 / det;
  o[0] =  c0 * id;
  o[1] = (a[2]*a[7] - a[1]*a[8]) * id;
  o[2] = (a[1]*a[5] - a[2]*a[4]) * id;
  o[3] = -c1 * id;
  o[4] = (a[0]*a[8] - a[2]*a[6]) * id;
  o[5] = (a[2]*a[3] - a[0]*a[5]) * id;
  o[6] =  c2 * id;
  o[7] = (a[1]*a[6] - a[0]*a[7]) * id;
  o[8] = (a[0]*a[4] - a[1]*a[3]) * id;
}

__global__ __launch_bounds__(256) void prep_all(
    const float* __restrict__ rots, const float* __restrict__ trans,
    const float* __restrict__ intr, const float* __restrict__ prot,
    const float* __restrict__ ptra, float* __restrict__ mats,
    const float* __restrict__ Wd, u16* __restrict__ PBh,
    float4* __restrict__ outT4, float4* __restrict__ hist4) {
  int bid = blockIdx.x;
  if (bid < 256) {
    int flat = bid * 256 + threadIdx.x;          // 65536 entries
    int j    = flat & 7;
    int o    = (flat >> 3) & 127;
    int i    = (flat >> 10) & 3;
    int half = (flat >> 12) & 1;
    int kb6  = flat >> 13;                       // 0..7
    int k    = kb6 * 64 + half * 32 + i * 8 + j; // 0..511
    float f  = (o < 123) ? Wd[o * 512 + k] : 0.f;
    PBh[flat] = f2bf(f);
    return;
  }
  if (bid > 256) {
    int i = (bid - 257) * 256 + threadIdx.x;
    float4 z = make_float4(0.f, 0.f, 0.f, 0.f);
    if (i < OUT_F4) outT4[i] = z;
    else if (i < OUT_F4 + HIST_F4) hist4[i - OUT_F4] = z;
    return;
  }
  int bn = threadIdx.x;
  if (bn >= NIMG) return;
  double pr[9], ik[9];
  for (int i = 0; i < 9; i++) { pr[i] = prot[bn*9 + i]; ik[i] = intr[bn*9 + i]; }
  double Minv[9], Kinv[9];
  inv3(pr, Minv);
  inv3(ik, Kinv);
  float* m = mats + bn*24;
  for (int i = 0; i < 9; i++) m[i] = (float)Minv[i];
  float kf[9];
  for (int i = 0; i < 9; i++) kf[i] = (float)Kinv[i];
  {
#pragma clang fp contract(off)
    for (int i = 0; i < 3; i++)
      for (int j = 0; j < 3; j++) {
        float s = rots[bn*9 + i*3 + 0] * kf[0*3 + j];
        s = s + rots[bn*9 + i*3 + 1] * kf[1*3 + j];
        s = s + rots[bn*9 + i*3 + 2] * kf[2*3 + j];
        m[9 + i*3 + j] = s;
      }
  }
  m[18] = ptra[bn*3 + 0]; m[19] = ptra[bn*3 + 1]; m[20] = ptra[bn*3 + 2];
  m[21] = trans[bn*3 + 0]; m[22] = trans[bn*3 + 1]; m[23] = trans[bn*3 + 2];
}

// ---------------------------------------------------------------------------
// Kernel 2: fused MFMA GEMM + softmax (r19/r22-validated gemm half, now
// standalone so gemm waves don't compete with geom waves for issue slots).
// ---------------------------------------------------------------------------
__global__ __launch_bounds__(256) void gemm_fused(const float* __restrict__ x,
    const u16* __restrict__ PBh, const float* __restrict__ bd,
    float* __restrict__ depth_ws, float* __restrict__ img_ws) {
  __shared__ __attribute__((aligned(16))) unsigned char smem[23040];
  int t = threadIdx.x;
  int l = t & 63, wid = t >> 6;
  int wr = wid >> 1, wc = wid & 1;
  int pixbase = blockIdx.x << 5;       // 704 = 22*32: tile stays in one image
  int bn = pixbase / NPIX;
  int pix0 = pixbase - bn * NPIX;
  const float* xb = x + (size_t)bn * 512 * NPIX + pix0;

  int a_c0   = (t >> 4) << 2;          // 0..60 (c quad)
  int a_pixt = (t & 15) << 1;          // 0..30 (pix pair)
  int b_o    = t & 127;
  int b_kh   = (t >> 7) << 5;          // 0 or 32

  float2 pa[4];
  u16x8 pbh[4];

#define LOADK(KB)                                                              \
  {                                                                            \
    pa[0] = *(const float2*)&xb[(size_t)((KB) + a_c0 + 0) * NPIX + a_pixt];    \
    pa[1] = *(const float2*)&xb[(size_t)((KB) + a_c0 + 1) * NPIX + a_pixt];    \
    pa[2] = *(const float2*)&xb[(size_t)((KB) + a_c0 + 2) * NPIX + a_pixt];    \
    pa[3] = *(const float2*)&xb[(size_t)((KB) + a_c0 + 3) * NPIX + a_pixt];    \
    size_t gb = ((((size_t)((KB) >> 6) << 3) + ((size_t)(t >> 7) << 2)) << 10) \
                + ((size_t)(t & 127) << 3);                                    \
    _Pragma("unroll")                                                          \
    for (int i = 0; i < 4; ++i) {                                              \
      pbh[i] = *(const u16x8*)(PBh + gb + ((size_t)i << 10));                  \
    }                                                                          \
  }

#define WRITEK()                                                               \
  {                                                                            \
    _Pragma("unroll")                                                          \
    for (int j = 0; j < 2; ++j) {                                              \
      float f0 = j ? pa[0].y : pa[0].x;                                        \
      float f1 = j ? pa[1].y : pa[1].x;                                        \
      float f2 = j ? pa[2].y : pa[2].x;                                        \
      float f3 = j ? pa[3].y : pa[3].x;                                        \
      bf16x4 hv = {(__bf16)f0, (__bf16)f1, (__bf16)f2, (__bf16)f3};            \
      int row = a_pixt + j;                                                    \
      *(bf16x4*)(smem + row * 144 + a_c0 * 2) = hv;                            \
    }                                                                          \
    _Pragma("unroll")                                                          \
    for (int i = 0; i < 4; ++i) {                                              \
      int kkb = (b_kh + (i << 3)) * 2;                                         \
      *(u16x8*)(smem + 4608 + b_o * 144 + kkb) = pbh[i];                       \
    }                                                                          \
  }

  f32x4 zero4 = {0.f, 0.f, 0.f, 0.f};
  f32x4 acc[4];
#pragma unroll
  for (int ni = 0; ni < 4; ni++) acc[ni] = zero4;

  LOADK(0);
  WRITEK();
  __syncthreads();

  for (int kb = 0; kb < 512; kb += 64) {
    if (kb + 64 < 512) LOADK(kb + 64);
#pragma unroll
    for (int h = 0; h < 2; ++h) {
      int kk2 = (h * 32 + ((l >> 4) << 3)) * 2;
      int arow = (wr << 4) + (l & 15);
      bf16x8 ah = *(const bf16x8*)(smem + arow * 144 + kk2);
#pragma unroll
      for (int ni = 0; ni < 4; ++ni) {
        int o = (wc << 6) + (ni << 4) + (l & 15);
        bf16x8 bh_ = *(const bf16x8*)(smem + 4608 + o * 144 + kk2);
        acc[ni] = __builtin_amdgcn_mfma_f32_16x16x32_bf16(ah, bh_, acc[ni], 0, 0, 0);
      }
    }
    __syncthreads();
    if (kb + 64 < 512) {
      WRITEK();
      __syncthreads();
    }
  }

  float* F = (float*)smem;
#pragma unroll
  for (int ni = 0; ni < 4; ++ni)
#pragma unroll
    for (int r = 0; r < 4; ++r) {
      int row = (wr << 4) + ((l >> 4) << 2) + r;
      int col = (wc << 6) + (ni << 4) + (l & 15);
      F[row * 132 + col] = acc[ni][r];
    }
  __syncthreads();

  int c = l;
  float bA = bd[c];
  float bI = bd[DB + c];
  for (int p = wid; p < 32; p += 4) {
    float fA = F[p * 132 + c] + bA;
    float fI = F[p * 132 + DB + c] + bI;
    float mv = (c < DB) ? fA : -3.4e38f;
#pragma unroll
    for (int ofs = 32; ofs > 0; ofs >>= 1) mv = fmaxf(mv, __shfl_xor(mv, ofs));
    float ev = (c < DB) ? __expf(fA - mv) : 0.f;
    float sv = ev;
#pragma unroll
    for (int ofs = 32; ofs > 0; ofs >>= 1) sv += __shfl_xor(sv, ofs);
    size_t rec = (size_t)(pixbase + p) << 6;
    if (c < DB) depth_ws[rec + c] = ev / sv;
    img_ws[rec + c] = fI;
  }
#undef LOADK
#undef WRITEK
}

// ---------------------------------------------------------------------------
// Kernel 3: geometry -> key+rank; SLC=32 + wave-run aggregation (r22-valid).
// ---------------------------------------------------------------------------
__global__ __launch_bounds__(256) void geom_k(const float* __restrict__ mats,
    int2* __restrict__ pr, int* __restrict__ hist) {
  int t = threadIdx.x;
  int wid = (blockIdx.x << 2) + (t >> 6);
  int lane = t & 63;
  int bn = wid / NPIX;
  int pix = wid - bn*NPIX;
  int b = bn / NCAM;
  int h = pix / 44, w = pix - h*44;
  const float* M = mats + bn*24;

  int code = -1;
  {
#pragma clang fp contract(off)
    float xs = (float)((double)w * (703.0 / 43.0));
    float ys = (float)(h * 17);
    float dval = (float)(lane + 1);
    float vx = xs - M[18], vy = ys - M[19], vz = dval - M[20];
    float qx = M[0]*vx + M[1]*vy + M[2]*vz;
    float qy = M[3]*vx + M[4]*vy + M[5]*vz;
    float qz = M[6]*vx + M[7]*vy + M[8]*vz;
    float rx = qx*qz, ry = qy*qz;
    float px = M[9]*rx  + M[10]*ry + M[11]*qz + M[21];
    float py = M[12]*rx + M[13]*ry + M[14]*qz + M[22];
    float pz = M[15]*rx + M[16]*ry + M[17]*qz + M[23];
    float gx = floorf((px - (-50.8f - 0.4f)) / 0.8f);
    float gy = floorf((py - (-50.8f - 0.4f)) / 0.8f);
    float gz = floorf((pz - (0.0f - 10.0f)) / 20.0f);
    bool kept = (lane < DB) && (gx >= 0.f) && (gx < 128.f) &&
                (gy >= 0.f) && (gy < 128.f) && (gz == 0.f);
    if (kept) code = (b << 14) + (int)gy * 128 + (int)gx;
  }

  bool kept = code >= 0;
  int prevc = __shfl_up(code, 1);
  bool leader = kept && (lane == 0 || prevc != code);
  u64 kept_mask = __ballot(kept);
  u64 lead_mask = __ballot(leader);
  int key = -1, r = 0;
  if (kept) {
    u64 le_mask = (lane == 63) ? ~0ULL : ((2ULL << lane) - 1);  // bits <= lane
    int lead_lane = 63 - __builtin_clzll(lead_mask & le_mask);
    int mykey = 0, rl = 0;
    if (leader) {
      u64 bound = (lead_mask | ~kept_mask) & ~le_mask;          // bits > lane
      int next = bound ? __builtin_ctzll(bound) : 64;
      int grp = next - lane;
      mykey = code * SLC + ((wid + lane) & (SLC - 1));
      rl = atomicAdd(&hist[mykey], grp);
    }
    key = __shfl(mykey, lead_lane);
    r = __shfl(rl, lead_lane) + (lane - lead_lane);
  }
  if (lane < DB) pr[(size_t)wid * DB + lane] = make_int2(key, r);
}

// ---------------------------------------------------------------------------
// Kernels 4a/4b: hierarchical exclusive scan of hist[NKEY=2M].
// ---------------------------------------------------------------------------
__global__ __launch_bounds__(256) void scan1_k(const int* __restrict__ hist,
    int* __restrict__ blockSums) {
  __shared__ int red[256];
  int t = threadIdx.x;
  const int4* h4 = (const int4*)(hist + (blockIdx.x << 10));
  int4 v = h4[t];
  red[t] = v.x + v.y + v.z + v.w;
  __syncthreads();
  for (int ofs = 128; ofs > 0; ofs >>= 1) {
    if (t < ofs) red[t] += red[t + ofs];
    __syncthreads();
  }
  if (t == 0) blockSums[blockIdx.x] = red[0];
}

__global__ __launch_bounds__(256) void scan23_k(int* __restrict__ hist,
    const int* __restrict__ blockSums, int* __restrict__ totalK) {
  __shared__ int red[256];
  __shared__ int buf[2][256];
  __shared__ int bpref;
  int t = threadIdx.x;
  int bid = blockIdx.x;
  int s0 = 0;
  for (int e = t; e < SCAN_BLKS; e += 256)
    if (e < bid) s0 += blockSums[e];
  red[t] = s0;
  __syncthreads();
  for (int ofs = 128; ofs > 0; ofs >>= 1) {
    if (t < ofs) red[t] += red[t + ofs];
    __syncthreads();
  }
  if (t == 0) bpref = red[0];
  __syncthreads();

  int4* h4 = (int4*)(hist + (bid << 10));
  int4 v = h4[t];
  int s = v.x + v.y + v.z + v.w;
  buf[0][t] = s;
  __syncthreads();
  int src = 0;
  for (int ofs = 1; ofs < 256; ofs <<= 1) {
    int vv = buf[src][t];
    if (t >= ofs) vv += buf[src][t - ofs];
    buf[src ^ 1][t] = vv;
    __syncthreads();
    src ^= 1;
  }
  int run = bpref + ((t == 0) ? 0 : buf[src][t - 1]);
  int4 o;
  o.x = run; run += v.x;
  o.y = run; run += v.y;
  o.z = run; run += v.z;
  o.w = run;
  h4[t] = o;
  if (bid == SCAN_BLKS - 1 && t == 255) *totalK = bpref + buf[src][255];
}

// ---------------------------------------------------------------------------
// Kernel 5: atomic-free placement: pos = offsets[key] + rank.
// ---------------------------------------------------------------------------
__global__ __launch_bounds__(256) void order_k(const int2* __restrict__ pr,
    const int* __restrict__ offsets, int2* __restrict__ sorted) {
  int p = blockIdx.x * 256 + threadIdx.x;
  if (p >= P_TOT) return;
  int2 e = pr[p];
  if (e.x >= 0) {
    int pos = offsets[e.x] + e.y;
    int bnpix = p / DB;
    int d = p - bnpix * DB;
    sorted[pos] = make_int2(e.x / SLC, (bnpix << 6) + d);
  }
}

// ---------------------------------------------------------------------------
// Kernel 6: segmented gather into voxel-major outT[b][vox][c].
// ---------------------------------------------------------------------------
__global__ __launch_bounds__(256) void gather_seg(const int2* __restrict__ sorted,
    const int* __restrict__ totalK,
    const float* __restrict__ depth_ws, const float* __restrict__ img_ws,
    float* __restrict__ outT) {
  int wid = (blockIdx.x << 2) + (threadIdx.x >> 6);
  int lane = threadIdx.x & 63;
  int K = *totalK;
  int start = wid * CHUNK;
  if (start >= K) return;
  int end = min(start + CHUNK, K);

  int2 s0 = sorted[start];
  int cur = s0.x;
  float acc = 0.f;
  for (int i = start; i < end; ++i) {
    int2 s = sorted[i];
    if (s.x != cur) {                     // wave-uniform branch
      unsafeAtomicAdd(&outT[((size_t)cur << 6) + lane], acc);
      acc = 0.f;
      cur = s.x;
    }
    float dep = depth_ws[s.y];                          // broadcast load
    float im  = img_ws[(s.y & 0x7FFFFFC0) + lane];      // coalesced 256B
    acc += dep * im;
  }
  unsafeAtomicAdd(&outT[((size_t)cur << 6) + lane], acc);
}

// ---------------------------------------------------------------------------
// Kernel 7: transpose outT[b][vox][c] -> out[b][c][vox]. 64x64 LDS tiles.
// ---------------------------------------------------------------------------
__global__ __launch_bounds__(256) void transpose_k(const float* __restrict__ outT,
    float* __restrict__ out) {
  __shared__ float tile[64][65];
  int b = blockIdx.x >> 8;               // 0..3
  int voxbase = (blockIdx.x & 255) << 6; // 0..16320
  int t = threadIdx.x;
#pragma unroll
  for (int i = 0; i < 16; ++i) {
    int idx = t + (i << 8);
    int row = idx >> 6, col = idx & 63;
    tile[row][col] = outT[(((size_t)b << 14) + voxbase + row) * 64 + col];
  }
  __syncthreads();
#pragma unroll
  for (int i = 0; i < 16; ++i) {
    int idx = t + (i << 8);
    int crow = idx >> 6, vl = idx & 63;
    out[(((size_t)(b << 6) + crow) << 14) + voxbase + vl] = tile[vl][crow];
  }
}

// ---------------------------------------------------------------------------
extern "C" void kernel_launch(void* const* d_in, const int* in_sizes, int n_in,
                              void* d_out, int out_size, void* d_ws, size_t ws_size,
                              hipStream_t stream) {
  const float* x    = (const float*)d_in[0];
  const float* rots = (const float*)d_in[1];
  const float* trn  = (const float*)d_in[2];
  const float* intr = (const float*)d_in[3];
  const float* prot = (const float*)d_in[4];
  const float* ptra = (const float*)d_in[5];
  const float* Wd   = (const float*)d_in[6];
  const float* bd   = (const float*)d_in[7];
  float* out = (float*)d_out;
  float* ws  = (float*)d_ws;

  // ws_size = 256 MiB; footprint ~50 MB.
  float* mats     = ws;                                    // 1024 floats
  float* depth_ws = ws + 1024;                             // 1,081,344
  float* img_ws   = depth_ws + (size_t)MPIX*64;            // 1,081,344
  int*   hist     = (int*)(img_ws + (size_t)MPIX*64);      // 2,097,152 (16B-aligned)
  int*   blockSums= hist + NKEY;                           // 2048
  int*   totalK   = blockSums + SCAN_BLKS;                 // 4 (pad)
  int2*  pr       = (int2*)(totalK + 4);                   // 996,864 int2
  int2*  sorted   = pr + P_TOT;                            // 996,864 int2
  float* outT     = (float*)(sorted + P_TOT);              // 4,194,304 floats
  u16*   PBh      = (u16*)(outT + (size_t)OUT_F4*4);       // 65,536 u16

  prep_all<<<257 + (OUT_F4 + HIST_F4 + 255)/256, 256, 0, stream>>>(
      rots, trn, intr, prot, ptra, mats, Wd, PBh, (float4*)outT, (float4*)hist);
  geom_k<<<GEOM_BLKS, 256, 0, stream>>>(mats, pr, hist);
  gemm_fused<<<GEMM_BLKS, 256, 0, stream>>>(x, PBh, bd, depth_ws, img_ws);
  scan1_k<<<SCAN_BLKS, 256, 0, stream>>>(hist, blockSums);
  scan23_k<<<SCAN_BLKS, 256, 0, stream>>>(hist, blockSums, totalK);
  order_k<<<(P_TOT + 255)/256, 256, 0, stream>>>(pr, hist, sorted);
  gather_seg<<<(P_TOT/CHUNK + 3)/4, 256, 0, stream>>>(sorted, totalK, depth_ws, img_ws, outT);
  transpose_k<<<NB*256, 256, 0, stream>>>(outT, out);
}

// Round 24
// 98.833 us; speedup vs baseline: 1.0874x; 1.0874x over previous
//
#include <hip/hip_runtime.h>

#define NPIX 704
#define NIMG 24
#define NB 4
#define NCAM 6
#define DB 59
#define CT 64
#define P_TOT (NIMG*NPIX*DB)   // 996864
#define NVOX 65536             // 4 batches * 128*128 (gz==0 only)
#define SLC 32                 // histogram slices (contention spreading)
#define NKEY (NVOX*SLC)        // 2,097,152
#define CHUNK 64
#define SCAN_BLKS (NKEY/1024)  // 2048
#define MPIX (NIMG*NPIX)       // 16896
#define OUT_F4 (NB*64*16384/4) // 1,048,576 float4 (outT)
#define HIST_F4 (NKEY/4)       // 524,288 float4 in hist
#define GEMM_BLKS (MPIX/32)    // 528
#define GEOM_BLKS (MPIX/4)     // 4224

typedef unsigned short u16;
typedef unsigned long long u64;
typedef __attribute__((ext_vector_type(8))) unsigned short u16x8;
typedef __attribute__((ext_vector_type(4))) __bf16 bf16x4;
typedef __attribute__((ext_vector_type(8))) __bf16 bf16x8;
typedef __attribute__((ext_vector_type(4))) float f32x4;

__device__ inline u16 f2bf(float f) {          // RN float->bf16
  unsigned u = __float_as_uint(f);
  u += 0x7FFFu + ((u >> 16) & 1u);
  return (u16)(u >> 16);
}

// ---------------------------------------------------------------------------
// Kernel 1: fused prep — blocks 0..255 pack W (bf16, staging order),
// block 256 per-(b,n) matrix prep, blocks 257.. zero outT + hist.
// ---------------------------------------------------------------------------
__device__ inline void inv3(const double a[9], double o[9]) {
  double c0 = a[4]*a[8] - a[5]*a[7];
  double c1 = a[3]*a[8] - a[5]*a[6];
  double c2 = a[3]*a[7] - a[4]*a[6];
  double det = a[0]*c0 - a[1]*c1 + a[2]*c2;
  double id = 1.0 / det;
  o[0] =  c0 * id;
  o[1] = (a[2]*a[7] - a[1]*a[8]) * id;
  o[2] = (a[1]*a[5] - a[2]*a[4]) * id;
  o[3] = -c1 * id;
  o[4] = (a[0]*a[8] - a[2]*a[6]) * id;
  o[5] = (a[2]*a[3] - a[0]*a[5]) * id;
  o[6] =  c2 * id;
  o[7] = (a[1]*a[6] - a[0]*a[7]) * id;
  o[8] = (a[0]*a[4] - a[1]*a[3]) * id;
}

__global__ __launch_bounds__(256) void prep_all(
    const float* __restrict__ rots, const float* __restrict__ trans,
    const float* __restrict__ intr, const float* __restrict__ prot,
    const float* __restrict__ ptra, float* __restrict__ mats,
    const float* __restrict__ Wd, u16* __restrict__ PBh,
    float4* __restrict__ outT4, float4* __restrict__ hist4) {
  int bid = blockIdx.x;
  if (bid < 256) {
    int flat = bid * 256 + threadIdx.x;          // 65536 entries
    int j    = flat & 7;
    int o    = (flat >> 3) & 127;
    int i    = (flat >> 10) & 3;
    int half = (flat >> 12) & 1;
    int kb6  = flat >> 13;                       // 0..7
    int k    = kb6 * 64 + half * 32 + i * 8 + j; // 0..511
    float f  = (o < 123) ? Wd[o * 512 + k] : 0.f;
    PBh[flat] = f2bf(f);
    return;
  }
  if (bid > 256) {
    int i = (bid - 257) * 256 + threadIdx.x;
    float4 z = make_float4(0.f, 0.f, 0.f, 0.f);
    if (i < OUT_F4) outT4[i] = z;
    else if (i < OUT_F4 + HIST_F4) hist4[i - OUT_F4] = z;
    return;
  }
  int bn = threadIdx.x;
  if (bn >= NIMG) return;
  double pr[9], ik[9];
  for (int i = 0; i < 9; i++) { pr[i] = prot[bn*9 + i]; ik[i] = intr[bn*9 + i]; }
  double Minv[9], Kinv[9];
  inv3(pr, Minv);
  inv3(ik, Kinv);
  float* m = mats + bn*24;
  for (int i = 0; i < 9; i++) m[i] = (float)Minv[i];
  float kf[9];
  for (int i = 0; i < 9; i++) kf[i] = (float)Kinv[i];
  {
#pragma clang fp contract(off)
    for (int i = 0; i < 3; i++)
      for (int j = 0; j < 3; j++) {
        float s = rots[bn*9 + i*3 + 0] * kf[0*3 + j];
        s = s + rots[bn*9 + i*3 + 1] * kf[1*3 + j];
        s = s + rots[bn*9 + i*3 + 2] * kf[2*3 + j];
        m[9 + i*3 + j] = s;
      }
  }
  m[18] = ptra[bn*3 + 0]; m[19] = ptra[bn*3 + 1]; m[20] = ptra[bn*3 + 2];
  m[21] = trans[bn*3 + 0]; m[22] = trans[bn*3 + 1]; m[23] = trans[bn*3 + 2];
}

// ---------------------------------------------------------------------------
// Kernel 2 (mega): blocks 0..527 = fused MFMA GEMM + softmax (r19-validated);
// blocks 528..4751 = geometry->key+rank with SLC=32 slicing AND wave-run
// aggregation: contiguous same-code lane runs elect a leader that does ONE
// atomicAdd(run_len); lanes derive rank = base + (lane - lead_lane).
// ---------------------------------------------------------------------------
__global__ __launch_bounds__(256) void mega_k(const float* __restrict__ x,
    const u16* __restrict__ PBh, const float* __restrict__ bd,
    float* __restrict__ depth_ws, float* __restrict__ img_ws,
    const float* __restrict__ mats, int2* __restrict__ pr,
    int* __restrict__ hist) {
  __shared__ __attribute__((aligned(16))) unsigned char smem[23040];
  int t = threadIdx.x;

  if (blockIdx.x >= GEMM_BLKS) {
    // ---------------- geom half ----------------
    int wid = ((blockIdx.x - GEMM_BLKS) << 2) + (t >> 6);
    int lane = t & 63;
    int bn = wid / NPIX;
    int pix = wid - bn*NPIX;
    int b = bn / NCAM;
    int h = pix / 44, w = pix - h*44;
    const float* M = mats + bn*24;

    int code = -1;
    {
#pragma clang fp contract(off)
      float xs = (float)((double)w * (703.0 / 43.0));
      float ys = (float)(h * 17);
      float dval = (float)(lane + 1);
      float vx = xs - M[18], vy = ys - M[19], vz = dval - M[20];
      float qx = M[0]*vx + M[1]*vy + M[2]*vz;
      float qy = M[3]*vx + M[4]*vy + M[5]*vz;
      float qz = M[6]*vx + M[7]*vy + M[8]*vz;
      float rx = qx*qz, ry = qy*qz;
      float px = M[9]*rx  + M[10]*ry + M[11]*qz + M[21];
      float py = M[12]*rx + M[13]*ry + M[14]*qz + M[22];
      float pz = M[15]*rx + M[16]*ry + M[17]*qz + M[23];
      float gx = floorf((px - (-50.8f - 0.4f)) / 0.8f);
      float gy = floorf((py - (-50.8f - 0.4f)) / 0.8f);
      float gz = floorf((pz - (0.0f - 10.0f)) / 20.0f);
      bool kept = (lane < DB) && (gx >= 0.f) && (gx < 128.f) &&
                  (gy >= 0.f) && (gy < 128.f) && (gz == 0.f);
      if (kept) code = (b << 14) + (int)gy * 128 + (int)gx;
    }

    bool kept = code >= 0;
    int prevc = __shfl_up(code, 1);
    bool leader = kept && (lane == 0 || prevc != code);
    u64 kept_mask = __ballot(kept);
    u64 lead_mask = __ballot(leader);
    int key = -1, r = 0;
    if (kept) {
      u64 le_mask = (lane == 63) ? ~0ULL : ((2ULL << lane) - 1);  // bits <= lane
      int lead_lane = 63 - __builtin_clzll(lead_mask & le_mask);
      int mykey = 0, rl = 0;
      if (leader) {
        u64 bound = (lead_mask | ~kept_mask) & ~le_mask;          // bits > lane
        int next = bound ? __builtin_ctzll(bound) : 64;
        int grp = next - lane;
        mykey = code * SLC + ((wid + lane) & (SLC - 1));
        rl = atomicAdd(&hist[mykey], grp);
      }
      key = __shfl(mykey, lead_lane);
      r = __shfl(rl, lead_lane) + (lane - lead_lane);
    }
    if (lane < DB) pr[(size_t)wid * DB + lane] = make_int2(key, r);
    return;
  }

  // ---------------- gemm half (r19-validated) ----------------
  int l = t & 63, wid = t >> 6;
  int wr = wid >> 1, wc = wid & 1;
  int pixbase = blockIdx.x << 5;       // 704 = 22*32: tile stays in one image
  int bn = pixbase / NPIX;
  int pix0 = pixbase - bn * NPIX;
  const float* xb = x + (size_t)bn * 512 * NPIX + pix0;

  int a_c0   = (t >> 4) << 2;          // 0..60 (c quad)
  int a_pixt = (t & 15) << 1;          // 0..30 (pix pair)
  int b_o    = t & 127;
  int b_kh   = (t >> 7) << 5;          // 0 or 32

  float2 pa[4];
  u16x8 pbh[4];

#define LOADK(KB)                                                              \
  {                                                                            \
    pa[0] = *(const float2*)&xb[(size_t)((KB) + a_c0 + 0) * NPIX + a_pixt];    \
    pa[1] = *(const float2*)&xb[(size_t)((KB) + a_c0 + 1) * NPIX + a_pixt];    \
    pa[2] = *(const float2*)&xb[(size_t)((KB) + a_c0 + 2) * NPIX + a_pixt];    \
    pa[3] = *(const float2*)&xb[(size_t)((KB) + a_c0 + 3) * NPIX + a_pixt];    \
    size_t gb = ((((size_t)((KB) >> 6) << 3) + ((size_t)(t >> 7) << 2)) << 10) \
                + ((size_t)(t & 127) << 3);                                    \
    _Pragma("unroll")                                                          \
    for (int i = 0; i < 4; ++i) {                                              \
      pbh[i] = *(const u16x8*)(PBh + gb + ((size_t)i << 10));                  \
    }                                                                          \
  }

#define WRITEK()                                                               \
  {                                                                            \
    _Pragma("unroll")                                                          \
    for (int j = 0; j < 2; ++j) {                                              \
      float f0 = j ? pa[0].y : pa[0].x;                                        \
      float f1 = j ? pa[1].y : pa[1].x;                                        \
      float f2 = j ? pa[2].y : pa[2].x;                                        \
      float f3 = j ? pa[3].y : pa[3].x;                                        \
      bf16x4 hv = {(__bf16)f0, (__bf16)f1, (__bf16)f2, (__bf16)f3};            \
      int row = a_pixt + j;                                                    \
      *(bf16x4*)(smem + row * 144 + a_c0 * 2) = hv;                            \
    }                                                                          \
    _Pragma("unroll")                                                          \
    for (int i = 0; i < 4; ++i) {                                              \
      int kkb = (b_kh + (i << 3)) * 2;                                         \
      *(u16x8*)(smem + 4608 + b_o * 144 + kkb) = pbh[i];                       \
    }                                                                          \
  }

  f32x4 zero4 = {0.f, 0.f, 0.f, 0.f};
  f32x4 acc[4];
#pragma unroll
  for (int ni = 0; ni < 4; ni++) acc[ni] = zero4;

  LOADK(0);
  WRITEK();
  __syncthreads();

  for (int kb = 0; kb < 512; kb += 64) {
    if (kb + 64 < 512) LOADK(kb + 64);
#pragma unroll
    for (int h = 0; h < 2; ++h) {
      int kk2 = (h * 32 + ((l >> 4) << 3)) * 2;
      int arow = (wr << 4) + (l & 15);
      bf16x8 ah = *(const bf16x8*)(smem + arow * 144 + kk2);
#pragma unroll
      for (int ni = 0; ni < 4; ++ni) {
        int o = (wc << 6) + (ni << 4) + (l & 15);
        bf16x8 bh_ = *(const bf16x8*)(smem + 4608 + o * 144 + kk2);
        acc[ni] = __builtin_amdgcn_mfma_f32_16x16x32_bf16(ah, bh_, acc[ni], 0, 0, 0);
      }
    }
    __syncthreads();
    if (kb + 64 < 512) {
      WRITEK();
      __syncthreads();
    }
  }

  float* F = (float*)smem;
#pragma unroll
  for (int ni = 0; ni < 4; ++ni)
#pragma unroll
    for (int r = 0; r < 4; ++r) {
      int row = (wr << 4) + ((l >> 4) << 2) + r;
      int col = (wc << 6) + (ni << 4) + (l & 15);
      F[row * 132 + col] = acc[ni][r];
    }
  __syncthreads();

  int c = l;
  float bA = bd[c];
  float bI = bd[DB + c];
  for (int p = wid; p < 32; p += 4) {
    float fA = F[p * 132 + c] + bA;
    float fI = F[p * 132 + DB + c] + bI;
    float mv = (c < DB) ? fA : -3.4e38f;
#pragma unroll
    for (int ofs = 32; ofs > 0; ofs >>= 1) mv = fmaxf(mv, __shfl_xor(mv, ofs));
    float ev = (c < DB) ? __expf(fA - mv) : 0.f;
    float sv = ev;
#pragma unroll
    for (int ofs = 32; ofs > 0; ofs >>= 1) sv += __shfl_xor(sv, ofs);
    size_t rec = (size_t)(pixbase + p) << 6;
    if (c < DB) depth_ws[rec + c] = ev / sv;
    img_ws[rec + c] = fI;
  }
#undef LOADK
#undef WRITEK
}

// ---------------------------------------------------------------------------
// Kernels 4a/4b: hierarchical exclusive scan of hist[NKEY=2M].
// ---------------------------------------------------------------------------
__global__ __launch_bounds__(256) void scan1_k(const int* __restrict__ hist,
    int* __restrict__ blockSums) {
  __shared__ int red[256];
  int t = threadIdx.x;
  const int4* h4 = (const int4*)(hist + (blockIdx.x << 10));
  int4 v = h4[t];
  red[t] = v.x + v.y + v.z + v.w;
  __syncthreads();
  for (int ofs = 128; ofs > 0; ofs >>= 1) {
    if (t < ofs) red[t] += red[t + ofs];
    __syncthreads();
  }
  if (t == 0) blockSums[blockIdx.x] = red[0];
}

__global__ __launch_bounds__(256) void scan23_k(int* __restrict__ hist,
    const int* __restrict__ blockSums, int* __restrict__ totalK) {
  __shared__ int red[256];
  __shared__ int buf[2][256];
  __shared__ int bpref;
  int t = threadIdx.x;
  int bid = blockIdx.x;
  int s0 = 0;
  for (int e = t; e < SCAN_BLKS; e += 256)
    if (e < bid) s0 += blockSums[e];
  red[t] = s0;
  __syncthreads();
  for (int ofs = 128; ofs > 0; ofs >>= 1) {
    if (t < ofs) red[t] += red[t + ofs];
    __syncthreads();
  }
  if (t == 0) bpref = red[0];
  __syncthreads();

  int4* h4 = (int4*)(hist + (bid << 10));
  int4 v = h4[t];
  int s = v.x + v.y + v.z + v.w;
  buf[0][t] = s;
  __syncthreads();
  int src = 0;
  for (int ofs = 1; ofs < 256; ofs <<= 1) {
    int vv = buf[src][t];
    if (t >= ofs) vv += buf[src][t - ofs];
    buf[src ^ 1][t] = vv;
    __syncthreads();
    src ^= 1;
  }
  int run = bpref + ((t == 0) ? 0 : buf[src][t - 1]);
  int4 o;
  o.x = run; run += v.x;
  o.y = run; run += v.y;
  o.z = run; run += v.z;
  o.w = run;
  h4[t] = o;
  if (bid == SCAN_BLKS - 1 && t == 255) *totalK = bpref + buf[src][255];
}

// ---------------------------------------------------------------------------
// Kernel 5: atomic-free placement: pos = offsets[key] + rank.
// ---------------------------------------------------------------------------
__global__ __launch_bounds__(256) void order_k(const int2* __restrict__ pr,
    const int* __restrict__ offsets, int2* __restrict__ sorted) {
  int p = blockIdx.x * 256 + threadIdx.x;
  if (p >= P_TOT) return;
  int2 e = pr[p];
  if (e.x >= 0) {
    int pos = offsets[e.x] + e.y;
    int bnpix = p / DB;
    int d = p - bnpix * DB;
    sorted[pos] = make_int2(e.x / SLC, (bnpix << 6) + d);
  }
}

// ---------------------------------------------------------------------------
// Kernel 6: segmented gather into voxel-major outT[b][vox][c].
// ---------------------------------------------------------------------------
__global__ __launch_bounds__(256) void gather_seg(const int2* __restrict__ sorted,
    const int* __restrict__ totalK,
    const float* __restrict__ depth_ws, const float* __restrict__ img_ws,
    float* __restrict__ outT) {
  int wid = (blockIdx.x << 2) + (threadIdx.x >> 6);
  int lane = threadIdx.x & 63;
  int K = *totalK;
  int start = wid * CHUNK;
  if (start >= K) return;
  int end = min(start + CHUNK, K);

  int2 s0 = sorted[start];
  int cur = s0.x;
  float acc = 0.f;
  for (int i = start; i < end; ++i) {
    int2 s = sorted[i];
    if (s.x != cur) {                     // wave-uniform branch
      unsafeAtomicAdd(&outT[((size_t)cur << 6) + lane], acc);
      acc = 0.f;
      cur = s.x;
    }
    float dep = depth_ws[s.y];                          // broadcast load
    float im  = img_ws[(s.y & 0x7FFFFFC0) + lane];      // coalesced 256B
    acc += dep * im;
  }
  unsafeAtomicAdd(&outT[((size_t)cur << 6) + lane], acc);
}

// ---------------------------------------------------------------------------
// Kernel 7: transpose outT[b][vox][c] -> out[b][c][vox]. 64x64 LDS tiles.
// ---------------------------------------------------------------------------
__global__ __launch_bounds__(256) void transpose_k(const float* __restrict__ outT,
    float* __restrict__ out) {
  __shared__ float tile[64][65];
  int b = blockIdx.x >> 8;               // 0..3
  int voxbase = (blockIdx.x & 255) << 6; // 0..16320
  int t = threadIdx.x;
#pragma unroll
  for (int i = 0; i < 16; ++i) {
    int idx = t + (i << 8);
    int row = idx >> 6, col = idx & 63;
    tile[row][col] = outT[(((size_t)b << 14) + voxbase + row) * 64 + col];
  }
  __syncthreads();
#pragma unroll
  for (int i = 0; i < 16; ++i) {
    int idx = t + (i << 8);
    int crow = idx >> 6, vl = idx & 63;
    out[(((size_t)(b << 6) + crow) << 14) + voxbase + vl] = tile[vl][crow];
  }
}

// ---------------------------------------------------------------------------
extern "C" void kernel_launch(void* const* d_in, const int* in_sizes, int n_in,
                              void* d_out, int out_size, void* d_ws, size_t ws_size,
                              hipStream_t stream) {
  const float* x    = (const float*)d_in[0];
  const float* rots = (const float*)d_in[1];
  const float* trn  = (const float*)d_in[2];
  const float* intr = (const float*)d_in[3];
  const float* prot = (const float*)d_in[4];
  const float* ptra = (const float*)d_in[5];
  const float* Wd   = (const float*)d_in[6];
  const float* bd   = (const float*)d_in[7];
  float* out = (float*)d_out;
  float* ws  = (float*)d_ws;

  // ws_size = 256 MiB; footprint ~50 MB.
  float* mats     = ws;                                    // 1024 floats
  float* depth_ws = ws + 1024;                             // 1,081,344
  float* img_ws   = depth_ws + (size_t)MPIX*64;            // 1,081,344
  int*   hist     = (int*)(img_ws + (size_t)MPIX*64);      // 2,097,152 (16B-aligned)
  int*   blockSums= hist + NKEY;                           // 2048
  int*   totalK   = blockSums + SCAN_BLKS;                 // 4 (pad)
  int2*  pr       = (int2*)(totalK + 4);                   // 996,864 int2
  int2*  sorted   = pr + P_TOT;                            // 996,864 int2
  float* outT     = (float*)(sorted + P_TOT);              // 4,194,304 floats
  u16*   PBh      = (u16*)(outT + (size_t)OUT_F4*4);       // 65,536 u16

  prep_all<<<257 + (OUT_F4 + HIST_F4 + 255)/256, 256, 0, stream>>>(
      rots, trn, intr, prot, ptra, mats, Wd, PBh, (float4*)outT, (float4*)hist);
  mega_k<<<GEMM_BLKS + GEOM_BLKS, 256, 0, stream>>>(
      x, PBh, bd, depth_ws, img_ws, mats, pr, hist);
  scan1_k<<<SCAN_BLKS, 256, 0, stream>>>(hist, blockSums);
  scan23_k<<<SCAN_BLKS, 256, 0, stream>>>(hist, blockSums, totalK);
  order_k<<<(P_TOT + 255)/256, 256, 0, stream>>>(pr, hist, sorted);
  gather_seg<<<(P_TOT/CHUNK + 3)/4, 256, 0, stream>>>(sorted, totalK, depth_ws, img_ws, outT);
  transpose_k<<<NB*256, 256, 0, stream>>>(outT, out);
}